// Round 2
// baseline (103.988 us; speedup 1.0000x reference)
//
#include <hip/hip_runtime.h>

// MiniBatchDiscrimination fused kernel for MI355X (gfx950).
// x: [32,16,16,256] f32, T: [256,64,8] f32, out: [32,16,16,320] f32
// Grid = 512 blocks: (hw pixel) x (B-column half). 2 blocks/CU.
// Phase 1: stage full x tile [32][256] in LDS (one barrier), passthrough half of x.
// Phase 2: barrier-free GEMM 32x256x256 (this block's 256 T-columns), 4n x 4t/thread.
// Phase 3: park M [32][258-stride] in LDS (aliased over x tile), pairwise exp(-L1).

namespace {
constexpr int kN = 32;            // batch
constexpr int kHW = 256;          // H*W
constexpr int kF = 256;           // features (= GEMM K)
constexpr int kB = 64;            // discrimination kernels
constexpr int kC = 8;             // kernel dims
constexpr int kT = kB * kC;       // 512 total T columns
constexpr int kTB = kT / 2;       // 256 columns per block
constexpr int kMstride = kTB + 2; // 258: dword-bank stride 2 -> 2-way (free)
constexpr int kOutRow = kF + kB;  // 320
}

__global__ __launch_bounds__(512, 4)
void mbd_fused(const float* __restrict__ x, const float* __restrict__ Tm,
               float* __restrict__ out) {
  // 33 KB LDS, aliased: phase 1-2 use first 8192 floats as x tile [32][256];
  // phase 3 uses all 8256 floats as M tile [32][258].
  __shared__ float lds[kN * kMstride];
  const int hw = blockIdx.x & (kHW - 1);
  const int bg = blockIdx.x >> 8;        // 0 or 1: which half of T columns
  const int tid = threadIdx.x;

  // ---- Phase 1: stage x tile [32][256]; pass through this block's x half ----
  const float4* x4 = (const float4*)x;
  float4* out4 = (float4*)out;
  float4* xs4 = (float4*)lds;
#pragma unroll
  for (int s = 0; s < 4; ++s) {
    const int v = tid + s * 512;     // 0..2047 float4 slots (32 rows x 64)
    const int n = v >> 6;
    const int f4 = v & 63;
    float4 val = x4[(size_t)n * (kHW * kF / 4) + (size_t)hw * (kF / 4) + f4];
    xs4[n * 64 + f4] = val;
    if ((f4 >> 5) == bg)             // each block writes half the x features
      out4[(size_t)(n * kHW + hw) * (kOutRow / 4) + f4] = val;
  }
  __syncthreads();

  // ---- Phase 2: GEMM, no barriers. 4 n-rows x 4 t-cols per thread. ----
  const int t0 = (tid & 63) * 4;     // 0..252 (local column)
  const int n0 = (tid >> 6) * 4;     // 0..28 (wave-uniform -> LDS broadcast)
  const float4* Tg = (const float4*)Tm + (size_t)bg * (kTB / 4);

  float4 acc[4];
#pragma unroll
  for (int r = 0; r < 4; ++r) acc[r] = make_float4(0.f, 0.f, 0.f, 0.f);

#pragma unroll 2
  for (int k = 0; k < kF; k += 4) {
    float4 av[4], tv[4];
#pragma unroll
    for (int r = 0; r < 4; ++r)
      av[r] = *(const float4*)&lds[(n0 + r) * kF + k];   // broadcast b128
#pragma unroll
    for (int q = 0; q < 4; ++q)
      tv[q] = Tg[(size_t)(k + q) * (kT / 4) + (t0 >> 2)]; // coalesced, L2-hot
#pragma unroll
    for (int q = 0; q < 4; ++q) {
#pragma unroll
      for (int r = 0; r < 4; ++r) {
        const float a = (&av[r].x)[q];
        acc[r].x = fmaf(a, tv[q].x, acc[r].x);
        acc[r].y = fmaf(a, tv[q].y, acc[r].y);
        acc[r].z = fmaf(a, tv[q].z, acc[r].z);
        acc[r].w = fmaf(a, tv[q].w, acc[r].w);
      }
    }
  }
  __syncthreads();   // all x-tile reads done; safe to overwrite with M

  // ---- Phase 3a: park M [32][kMstride] in LDS (aliased) ----
#pragma unroll
  for (int r = 0; r < 4; ++r) {
    const int base = (n0 + r) * kMstride + t0;   // even index -> 8B aligned
    *(float2*)&lds[base]     = make_float2(acc[r].x, acc[r].y);
    *(float2*)&lds[base + 2] = make_float2(acc[r].z, acc[r].w);
  }
  __syncthreads();

  // ---- Phase 3b: pairwise exp(-L1). 1024 tasks (b_local, i); 2/thread. ----
#pragma unroll
  for (int s = 0; s < 2; ++s) {
    const int task = tid + s * 512;  // 0..1023
    const int b = task >> 5;         // 0..31 local b
    const int i = task & 31;         // sample index
    const float* Mi = &lds[i * kMstride + b * kC];
    float mi[8];
#pragma unroll
    for (int c2 = 0; c2 < 4; ++c2) {
      float2 v = *(const float2*)&Mi[c2 * 2];
      mi[c2 * 2] = v.x; mi[c2 * 2 + 1] = v.y;
    }
    float ob = 0.f;
#pragma unroll 4
    for (int j = 0; j < kN; ++j) {
      const float* Mj = &lds[j * kMstride + b * kC];  // broadcast per half-wave
      float nrm = 0.f;
#pragma unroll
      for (int c2 = 0; c2 < 4; ++c2) {
        float2 v = *(const float2*)&Mj[c2 * 2];
        nrm += fabsf(mi[c2 * 2] - v.x);
        nrm += fabsf(mi[c2 * 2 + 1] - v.y);
      }
      ob += __expf(-nrm);
    }
    out[(size_t)(i * kHW + hw) * kOutRow + kF + bg * 32 + b] = ob;
  }
}

extern "C" void kernel_launch(void* const* d_in, const int* in_sizes, int n_in,
                              void* d_out, int out_size, void* d_ws, size_t ws_size,
                              hipStream_t stream) {
  const float* x = (const float*)d_in[0];   // [32,16,16,256]
  const float* T = (const float*)d_in[1];   // [256,64,8]
  float* out = (float*)d_out;               // [32,16,16,320]
  (void)in_sizes; (void)n_in; (void)out_size; (void)d_ws; (void)ws_size;
  mbd_fused<<<dim3(2 * kHW), dim3(512), 0, stream>>>(x, T, out);
}

// Round 3
// 80.046 us; speedup vs baseline: 1.2991x; 1.2991x over previous
//
#include <hip/hip_runtime.h>
#include <hip/hip_bf16.h>

// MiniBatchDiscrimination via bf16 MFMA (gfx950).
// x: [32,16,16,256] f32, T: [256,64,8] f32, out: [32,16,16,320] f32.
// Kernel 1: T [256k][512t] f32 -> Tt [512t][256k] bf16 in d_ws.
// Kernel 2: 512 blocks (256 pixels x 2 t-halves), 512 threads:
//   stage x -> LDS A-frags (bf16) + f32 passthrough, MFMA 16x16x32 GEMM,
//   M tile bf16 in LDS, pairwise exp(-L1) out of LDS.

namespace {
constexpr int kN = 32;
constexpr int kHW = 256;
constexpr int kF = 256;          // GEMM K
constexpr int kB = 64;
constexpr int kOutRow = 320;
constexpr int kMstride = 264;    // 256 + 8 pad (ushorts); 528 B row, 16B-aligned
}

using frag_ab = __attribute__((ext_vector_type(8))) short;   // 8 bf16
using frag_cd = __attribute__((ext_vector_type(4))) float;   // 4 f32

__device__ inline unsigned short f2bf(float f) {
  union { __hip_bfloat16 h; unsigned short u; } c;
  c.h = __float2bfloat16(f);
  return c.u;
}

__device__ inline void unpack8(const uint4& m, float* f) {
  f[0] = __uint_as_float(m.x << 16);  f[1] = __uint_as_float(m.x & 0xffff0000u);
  f[2] = __uint_as_float(m.y << 16);  f[3] = __uint_as_float(m.y & 0xffff0000u);
  f[4] = __uint_as_float(m.z << 16);  f[5] = __uint_as_float(m.z & 0xffff0000u);
  f[6] = __uint_as_float(m.w << 16);  f[7] = __uint_as_float(m.w & 0xffff0000u);
}

// ---- Kernel 1: transpose + convert T -> Tt bf16 [512][256] ----
__global__ __launch_bounds__(256)
void transpose_T(const float* __restrict__ T, unsigned short* __restrict__ Tt) {
  __shared__ unsigned short tile[64 * 72];   // [t-local][72] (144 B rows, 16B-aligned)
  const int kt = blockIdx.x >> 3;            // 0..3 (k tile of 64)
  const int tt = blockIdx.x & 7;             // 0..7 (t tile of 64)
  const int k0 = kt * 64, t0 = tt * 64;
  const int tid = threadIdx.x;
#pragma unroll
  for (int s = 0; s < 4; ++s) {
    const int r = (tid >> 4) + s * 16;       // k row 0..63
    const int c = (tid & 15) * 4;            // t col
    float4 v = *(const float4*)&T[(size_t)(k0 + r) * 512 + t0 + c];
    tile[(c + 0) * 72 + r] = f2bf(v.x);
    tile[(c + 1) * 72 + r] = f2bf(v.y);
    tile[(c + 2) * 72 + r] = f2bf(v.z);
    tile[(c + 3) * 72 + r] = f2bf(v.w);
  }
  __syncthreads();
#pragma unroll
  for (int s = 0; s < 2; ++s) {
    const int tr = (tid >> 3) + s * 32;      // 0..63
    const int kc = (tid & 7) * 8;            // 0..56
    uint4 o = *(const uint4*)&tile[tr * 72 + kc];
    *(uint4*)&Tt[(size_t)(t0 + tr) * 256 + k0 + kc] = o;
  }
}

// ---- Kernel 2: fused GEMM + pairwise ----
__global__ __launch_bounds__(512, 4)
void mbd_main(const float* __restrict__ x, const unsigned short* __restrict__ Tt,
              float* __restrict__ out) {
  __shared__ uint4 Afrag[2 * 8 * 64];              // 16 KB: [rt][kt][lane], 8 bf16 each
  __shared__ unsigned short Mlds[kN * kMstride];   // 16.5 KB: [n][264]
  const int hw = blockIdx.x & (kHW - 1);
  const int bg = blockIdx.x >> 8;                  // t-half (0/1)
  const int tid = threadIdx.x;
  const int l = tid & 63, w = tid >> 6;

  // Phase 1: stage x -> A-frags (bf16) + passthrough this half's x features.
  const float4* x4 = (const float4*)x;
  float4* out4 = (float4*)out;
#pragma unroll
  for (int s = 0; s < 2; ++s) {
    const int task = tid + s * 512;        // 1024 tasks: 32 n x 32 k-groups
    const int n = task >> 5;
    const int k8 = task & 31;              // group of 8 k
    const size_t xb = (size_t)n * (kHW * kF / 4) + (size_t)hw * (kF / 4) + k8 * 2;
    float4 v0 = x4[xb];
    float4 v1 = x4[xb + 1];
    if ((k8 >> 4) == bg) {                 // each block writes half the x features
      const size_t ob = (size_t)(n * kHW + hw) * (kOutRow / 4) + k8 * 2;
      out4[ob] = v0;
      out4[ob + 1] = v1;
    }
    uint4 p;
    p.x = (unsigned)f2bf(v0.x) | ((unsigned)f2bf(v0.y) << 16);
    p.y = (unsigned)f2bf(v0.z) | ((unsigned)f2bf(v0.w) << 16);
    p.z = (unsigned)f2bf(v1.x) | ((unsigned)f2bf(v1.y) << 16);
    p.w = (unsigned)f2bf(v1.z) | ((unsigned)f2bf(v1.w) << 16);
    const int rt = n >> 4, kt = k8 >> 2, ln = (n & 15) | ((k8 & 3) << 4);
    Afrag[(rt * 8 + kt) * 64 + ln] = p;
  }
  __syncthreads();

  // Phase 2: MFMA GEMM. Wave w owns t-tiles {2w, 2w+1} of this half.
  frag_cd acc[2][2] = {};                  // [q][rt]
#pragma unroll
  for (int kt = 0; kt < 8; ++kt) {
    uint4 a0 = Afrag[(0 * 8 + kt) * 64 + l];
    uint4 a1 = Afrag[(1 * 8 + kt) * 64 + l];
    const int krow = kt * 32 + (l >> 4) * 8;
#pragma unroll
    for (int q = 0; q < 2; ++q) {
      const int tcol = bg * 256 + (w * 2 + q) * 16 + (l & 15);
      uint4 b = *(const uint4*)&Tt[(size_t)tcol * 256 + krow];
      frag_ab af0 = __builtin_bit_cast(frag_ab, a0);
      frag_ab af1 = __builtin_bit_cast(frag_ab, a1);
      frag_ab bf = __builtin_bit_cast(frag_ab, b);
      acc[q][0] = __builtin_amdgcn_mfma_f32_16x16x32_bf16(af0, bf, acc[q][0], 0, 0, 0);
      acc[q][1] = __builtin_amdgcn_mfma_f32_16x16x32_bf16(af1, bf, acc[q][1], 0, 0, 0);
    }
  }

  // Park M (bf16) in LDS. C/D layout: col = l&15, row = (l>>4)*4 + reg.
#pragma unroll
  for (int q = 0; q < 2; ++q)
#pragma unroll
    for (int rt = 0; rt < 2; ++rt)
#pragma unroll
      for (int r = 0; r < 4; ++r) {
        const int n = rt * 16 + (l >> 4) * 4 + r;
        const int t = (w * 2 + q) * 16 + (l & 15);
        Mlds[n * kMstride + t] = f2bf(acc[q][rt][r]);
      }
  __syncthreads();

  // Phase 3: pairwise exp(-L1). Thread: one local b (0..31), two i's.
  const int b = tid >> 4;                  // 0..31
  const int i0 = (tid & 15) * 2;
  float mi[2][8];
#pragma unroll
  for (int ii = 0; ii < 2; ++ii) {
    uint4 m = *(const uint4*)&Mlds[(i0 + ii) * kMstride + b * 8];
    unpack8(m, mi[ii]);
  }
  float ob0 = 0.f, ob1 = 0.f;
#pragma unroll 4
  for (int j = 0; j < kN; ++j) {
    uint4 m = *(const uint4*)&Mlds[j * kMstride + b * 8];
    float mj[8];
    unpack8(m, mj);
    float n0 = 0.f, n1 = 0.f;
#pragma unroll
    for (int c = 0; c < 8; ++c) {
      n0 += fabsf(mi[0][c] - mj[c]);       // abs folds into add's input modifier
      n1 += fabsf(mi[1][c] - mj[c]);
    }
    ob0 += __expf(-n0);
    ob1 += __expf(-n1);
  }
  const int bglob = kF + bg * 32 + b;
  out[(size_t)(i0 * kHW + hw) * kOutRow + bglob] = ob0;
  out[(size_t)((i0 + 1) * kHW + hw) * kOutRow + bglob] = ob1;
}

extern "C" void kernel_launch(void* const* d_in, const int* in_sizes, int n_in,
                              void* d_out, int out_size, void* d_ws, size_t ws_size,
                              hipStream_t stream) {
  const float* x = (const float*)d_in[0];     // [32,16,16,256]
  const float* T = (const float*)d_in[1];     // [256,64,8] = [256][512]
  float* out = (float*)d_out;                 // [32,16,16,320]
  unsigned short* Tt = (unsigned short*)d_ws; // 512*256 bf16 = 256 KB
  (void)in_sizes; (void)n_in; (void)out_size; (void)ws_size;
  transpose_T<<<dim3(32), dim3(256), 0, stream>>>(T, Tt);
  mbd_main<<<dim3(2 * kHW), dim3(512), 0, stream>>>(x, Tt, out);
}